// Round 2
// baseline (524.347 us; speedup 1.0000x reference)
//
#include <hip/hip_runtime.h>
#include <stdint.h>

typedef _Float16 half2v __attribute__((ext_vector_type(2)));
typedef _Float16 half4 __attribute__((ext_vector_type(4)));
typedef _Float16 half8 __attribute__((ext_vector_type(8)));
typedef float floatx4 __attribute__((ext_vector_type(4)));
typedef float float4u __attribute__((ext_vector_type(4), aligned(8)));

#define TPB 256
#define ENC_ROW 20

__device__ __forceinline__ half2v pkrtz(float a, float b) {
    return __builtin_bit_cast(half2v, __builtin_amdgcn_cvt_pkrtz(a, b));
}

__device__ __forceinline__ half4 relu_pack(floatx4 c) {
    half2v lo = pkrtz(fmaxf(c[0], 0.f), fmaxf(c[1], 0.f));
    half2v hi = pkrtz(fmaxf(c[2], 0.f), fmaxf(c[3], 0.f));
    half4 r;
    r[0] = lo[0]; r[1] = lo[1]; r[2] = hi[0]; r[3] = hi[1];
    return r;
}

// ---------------- combined prep: tables (f16 x 2^13) + weight frags ---------
// Blocks [0,8192): convert 8*262144 float2 table entries to half2 scaled 2^13.
// Blocks [8192,8244): build MFMA A-fragment-ordered f16 weights.
// One dispatch instead of two removes one inter-dispatch bubble.
__global__ void prep_all(const float* __restrict__ tables,
                         uint32_t* __restrict__ tf,
                         const float* __restrict__ w_in,
                         const float* __restrict__ w_hidden,
                         _Float16* __restrict__ ws) {
    int b = blockIdx.x;
    if (b < 8192) {
        int i = b * 256 + threadIdx.x;
        float2 v = ((const float2*)tables)[i];
        half2v h;
        h[0] = (_Float16)(v.x * 8192.f);
        h[1] = (_Float16)(v.y * 8192.f);
        tf[i] = __builtin_bit_cast(uint32_t, h);
    } else {
        int i = (b - 8192) * 256 + threadIdx.x;
        if (i < 1024) {
            int j = i & 3, lane = (i >> 2) & 63, mt = i >> 8;
            int k = ((lane >> 4) & 3) * 4 + j;
            int n = mt * 16 + (lane & 15);
            ws[i] = (_Float16)w_in[k * 64 + n];
        } else if (i < 13312) {
            int t = i - 1024;
            int j = t & 3, lane = (t >> 2) & 63;
            int mt = (t >> 8) & 3, kt = (t >> 10) & 3, layer = t >> 12;
            int k = kt * 16 + ((lane >> 4) & 3) * 4 + j;
            int n = mt * 16 + (lane & 15);
            ws[i] = (_Float16)w_hidden[layer * 4096 + k * 64 + n];
        }
    }
}

// ---------------- standalone weight prep (fallback path only) ---------------
__global__ void prep_weights(const float* __restrict__ w_in,
                             const float* __restrict__ w_hidden,
                             _Float16* __restrict__ ws) {
    int i = blockIdx.x * 256 + threadIdx.x;
    if (i < 1024) {
        int j = i & 3, lane = (i >> 2) & 63, mt = i >> 8;
        int k = ((lane >> 4) & 3) * 4 + j;
        int n = mt * 16 + (lane & 15);
        ws[i] = (_Float16)w_in[k * 64 + n];
    } else if (i < 13312) {
        int t = i - 1024;
        int j = t & 3, lane = (t >> 2) & 63;
        int mt = (t >> 8) & 3, kt = (t >> 10) & 3, layer = t >> 12;
        int k = kt * 16 + ((lane >> 4) & 3) * 4 + j;
        int n = mt * 16 + (lane & 15);
        ws[i] = (_Float16)w_hidden[layer * 4096 + k * 64 + n];
    }
}

// =================== FUSED: encode (f16 tables, L0-3 in LDS) + MLP ==========
// r1 lesson: fusing at 37 KB LDS/block capped occupancy at 4 blocks/CU (42%)
// and the latency-bound gathers lost their hiding. The three LDS regions are
// never live at once: ltab+l3tab (26.7 KB) are fully consumed before encbuf
// (10 KB) is written. Alias encbuf onto the table region with one extra
// __syncthreads -> 26.7 KB/block -> 6 blocks/CU (24 waves, 75%).
// Scatter discipline unchanged (scalar dword gathers only; 32/pt).
__global__ __launch_bounds__(TPB, 6) void fused_kernel(
    const float* __restrict__ x,
    const float* __restrict__ mesh_min,
    const float* __restrict__ mesh_max,
    const float* __restrict__ tables,   // fp32 originals (levels 0-2 LDS build)
    const uint32_t* __restrict__ tabs,  // [8][262144] half2 (scaled by 2^13)
    const _Float16* __restrict__ ws,
    const float* __restrict__ w_out,
    float* __restrict__ out,
    int N) {
    // Phase 1 layout: ltab (881 float2 = 7048 B) | l3tab (4913 u32 = 19652 B)
    // Phase 2 (after barrier): encbuf[4][64][ENC_ROW] f16 = 10240 B, aliased at 0.
    __shared__ __align__(16) char smem[26700];
    float2* ltab = (float2*)smem;
    uint32_t* l3tab = (uint32_t*)(smem + 7048);
    _Float16 (*encbuf)[64][ENC_ROW] = (_Float16 (*)[64][ENC_ROW])smem;

    const int wave = threadIdx.x >> 6;
    const int lane = threadIdx.x & 63;
    const int l15 = lane & 15;
    const int quad = lane >> 4;
    const int wavebase = blockIdx.x * TPB + wave * 64;
    const int p = wavebase + lane;

    // ---- build LDS (coalesced) ----
    {
        const float2* t0 = (const float2*)tables;
        for (int i = threadIdx.x; i < 27; i += TPB) ltab[i] = t0[i];
        const float2* t1 = (const float2*)(tables + 1 * 524288);
        for (int i = threadIdx.x; i < 125; i += TPB) ltab[27 + i] = t1[i];
        const float2* t2 = (const float2*)(tables + 2 * 524288);
        for (int i = threadIdx.x; i < 729; i += TPB) ltab[152 + i] = t2[i];
        const uint32_t* t3 = tabs + 3 * 262144;
        for (int i = threadIdx.x; i < 4913; i += TPB) l3tab[i] = t3[i];
    }

    float mn0 = mesh_min[0], mn1 = mesh_min[1], mn2 = mesh_min[2];
    float mx0 = mesh_max[0], mx1 = mesh_max[1], mx2 = mesh_max[2];
    float ux = (x[3 * p + 0] - mn0) / (mx0 - mn0);
    float uy = (x[3 * p + 1] - mn1) / (mx1 - mn1);
    float uz = (x[3 * p + 2] - mn2) / (mx2 - mn2);

    float ef[16];
    float wl[3][3];
    uint32_t g[24];   // hashed gathers (levels 5-7), issued back-to-back
    uint32_t g4[8];   // level-4 dense gathers
    float w4x, w4y, w4z;

    // ---- hashed levels 5-7: 24 scalar-dword gathers ----
#pragma unroll
    for (int l = 0; l < 3; ++l) {
        const int res = 64 << l;  // 64, 128, 256
        const uint32_t* tab = tabs + (size_t)(l + 5) * 262144;
        float px = ux * (float)res, py = uy * (float)res, pz = uz * (float)res;
        int cx = (int)floorf(px), cy = (int)floorf(py), cz = (int)floorf(pz);
        wl[l][0] = px - (float)cx;
        wl[l][1] = py - (float)cy;
        wl[l][2] = pz - (float)cz;
        uint32_t hy0 = (uint32_t)cy * 2654435761u, hy1 = (uint32_t)(cy + 1) * 2654435761u;
        uint32_t hz0 = (uint32_t)cz * 805459861u,  hz1 = (uint32_t)(cz + 1) * 805459861u;
#pragma unroll
        for (int c = 0; c < 4; ++c) {
            uint32_t hyz = ((c & 1) ? hy1 : hy0) ^ ((c & 2) ? hz1 : hz0);
            uint32_t i0 = ((uint32_t)cx ^ hyz) & 262143u;
            uint32_t i1 = ((uint32_t)(cx + 1) ^ hyz) & 262143u;
            g[l * 8 + 2 * c + 0] = tab[i0];
            g[l * 8 + 2 * c + 1] = tab[i1];
        }
    }

    // ---- dense level 4: 8 scalar-dword gathers, issued now, consumed later ----
    {
        const int s = 33;
        const uint32_t* tab = tabs + (size_t)4 * 262144;
        float px = ux * 32.f, py = uy * 32.f, pz = uz * 32.f;
        int cx = (int)floorf(px), cy = (int)floorf(py), cz = (int)floorf(pz);
        w4x = px - (float)cx; w4y = py - (float)cy; w4z = pz - (float)cz;
#pragma unroll
        for (int c = 0; c < 4; ++c) {
            int Y = cy + ((c & 1) ? 1 : 0);
            int Z = cz + ((c & 2) ? 1 : 0);
            int i0 = cx + Y * s + Z * s * s;
            g4[2 * c + 0] = tab[i0];
            g4[2 * c + 1] = tab[i0 + 1];
        }
    }

    __syncthreads();  // LDS tables ready; in-flight global gathers keep draining

    // ---- levels 0-2 from LDS (fp32), scale to match f16 tables ----
#pragma unroll
    for (int l = 0; l < 3; ++l) {
        const int res = 2 << l;
        const int s = res + 1;
        const int base = (l == 0) ? 0 : (l == 1) ? 27 : 152;
        float px = ux * (float)res, py = uy * (float)res, pz = uz * (float)res;
        int cx = (int)floorf(px), cy = (int)floorf(py), cz = (int)floorf(pz);
        float wx = px - (float)cx, wy = py - (float)cy, wz = pz - (float)cz;
        float f0 = 0.f, f1 = 0.f;
#pragma unroll
        for (int c = 0; c < 4; ++c) {
            int i0 = base + cx + (cy + ((c & 1) ? 1 : 0)) * s + (cz + ((c & 2) ? 1 : 0)) * s * s;
            float wyz = ((c & 1) ? wy : 1.f - wy) * ((c & 2) ? wz : 1.f - wz);
            float2 e0 = ltab[i0];
            float2 e1 = ltab[i0 + 1];
            f0 += wyz * (e0.x + wx * (e1.x - e0.x));
            f1 += wyz * (e0.y + wx * (e1.y - e0.y));
        }
        ef[2 * l + 0] = f0 * 8192.f;
        ef[2 * l + 1] = f1 * 8192.f;
    }

    // ---- level 3 from LDS (half2, pre-scaled) ----
    {
        const int s = 17;
        float px = ux * 16.f, py = uy * 16.f, pz = uz * 16.f;
        int cx = (int)floorf(px), cy = (int)floorf(py), cz = (int)floorf(pz);
        float wx = px - (float)cx, wy = py - (float)cy, wz = pz - (float)cz;
        float f0 = 0.f, f1 = 0.f;
#pragma unroll
        for (int c = 0; c < 4; ++c) {
            int i0 = cx + (cy + ((c & 1) ? 1 : 0)) * s + (cz + ((c & 2) ? 1 : 0)) * s * s;
            float wyz = ((c & 1) ? wy : 1.f - wy) * ((c & 2) ? wz : 1.f - wz);
            half2v e0 = __builtin_bit_cast(half2v, l3tab[i0]);
            half2v e1 = __builtin_bit_cast(half2v, l3tab[i0 + 1]);
            f0 += wyz * ((float)e0[0] + wx * ((float)e1[0] - (float)e0[0]));
            f1 += wyz * ((float)e0[1] + wx * ((float)e1[1] - (float)e0[1]));
        }
        ef[6] = f0;
        ef[7] = f1;
    }

    // ---- level 4 from buffered gathers ----
    {
        float f0 = 0.f, f1 = 0.f;
#pragma unroll
        for (int c = 0; c < 4; ++c) {
            float wyz = ((c & 1) ? w4y : 1.f - w4y) * ((c & 2) ? w4z : 1.f - w4z);
            half2v e0 = __builtin_bit_cast(half2v, g4[2 * c + 0]);
            half2v e1 = __builtin_bit_cast(half2v, g4[2 * c + 1]);
            f0 += wyz * ((float)e0[0] + w4x * ((float)e1[0] - (float)e0[0]));
            f1 += wyz * ((float)e0[1] + w4x * ((float)e1[1] - (float)e0[1]));
        }
        ef[8] = f0;
        ef[9] = f1;
    }

    // ---- hashed levels 5-7 ----
#pragma unroll
    for (int l = 0; l < 3; ++l) {
        float wx = wl[l][0], wy = wl[l][1], wz = wl[l][2];
        float f0 = 0.f, f1 = 0.f;
#pragma unroll
        for (int c = 0; c < 4; ++c) {
            float wyz = ((c & 1) ? wy : 1.f - wy) * ((c & 2) ? wz : 1.f - wz);
            half2v e0 = __builtin_bit_cast(half2v, g[l * 8 + 2 * c + 0]);
            half2v e1 = __builtin_bit_cast(half2v, g[l * 8 + 2 * c + 1]);
            f0 += wyz * ((float)e0[0] + wx * ((float)e1[0] - (float)e0[0]));
            f1 += wyz * ((float)e0[1] + wx * ((float)e1[1] - (float)e0[1]));
        }
        ef[10 + 2 * l + 0] = f0;
        ef[10 + 2 * l + 1] = f1;
    }

    // ---- barrier: all table reads done, safe to alias encbuf over tables ----
    __syncthreads();

    // ---- pack to per-wave LDS staging (wave-synchronous) ----
#pragma unroll
    for (int v = 0; v < 4; ++v) {
        half2v lo = pkrtz(ef[4 * v + 0], ef[4 * v + 1]);
        half2v hi = pkrtz(ef[4 * v + 2], ef[4 * v + 3]);
        half4 t;
        t[0] = lo[0]; t[1] = lo[1]; t[2] = hi[0]; t[3] = hi[1];
        *(half4*)&encbuf[wave][lane][v * 4] = t;
    }

    // ---- MLP layer 1: enc(16) -> 64, D = Win^T * Enc^T ----
    floatx4 C[4][4];
    {
        half4 b[4];
#pragma unroll
        for (int nt = 0; nt < 4; ++nt)
            b[nt] = *(const half4*)&encbuf[wave][nt * 16 + l15][quad * 4];
#pragma unroll
        for (int mt = 0; mt < 4; ++mt) {
            half4 a = *(const half4*)(ws + mt * 256 + lane * 4);
#pragma unroll
            for (int nt = 0; nt < 4; ++nt) {
                floatx4 zero = {0.f, 0.f, 0.f, 0.f};
                C[mt][nt] = __builtin_amdgcn_mfma_f32_16x16x16f16(a, b[nt], zero, 0, 0, 0);
            }
        }
    }

    // ---- layers 2..4: 64 -> 64; C regs (relu+pack) ARE the next B-frags ----
#pragma unroll
    for (int layer = 0; layer < 3; ++layer) {
        half4 b[4][4];  // [kt][nt]
#pragma unroll
        for (int kt = 0; kt < 4; ++kt)
#pragma unroll
            for (int nt = 0; nt < 4; ++nt)
                b[kt][nt] = relu_pack(C[kt][nt]);
#pragma unroll
        for (int mt = 0; mt < 4; ++mt) {
            half4 a[4];
#pragma unroll
            for (int kt = 0; kt < 4; ++kt)
                a[kt] = *(const half4*)(ws + 1024 + ((layer * 4 + kt) * 4 + mt) * 256 + lane * 4);
#pragma unroll
            for (int nt = 0; nt < 4; ++nt) {
                floatx4 acc = {0.f, 0.f, 0.f, 0.f};
#pragma unroll
                for (int kt = 0; kt < 4; ++kt)
                    acc = __builtin_amdgcn_mfma_f32_16x16x16f16(a[kt], b[kt][nt], acc, 0, 0, 0);
                C[mt][nt] = acc;
            }
        }
    }

    // ---- output layer: relu(h4) . w_out, quad-reduce, unscale ----
    {
        float s[4] = {0.f, 0.f, 0.f, 0.f};
#pragma unroll
        for (int mt = 0; mt < 4; ++mt) {
            float4 wo = *(const float4*)(w_out + mt * 16 + quad * 4);
#pragma unroll
            for (int nt = 0; nt < 4; ++nt) {
                s[nt] = fmaf(fmaxf(C[mt][nt][0], 0.f), wo.x, s[nt]);
                s[nt] = fmaf(fmaxf(C[mt][nt][1], 0.f), wo.y, s[nt]);
                s[nt] = fmaf(fmaxf(C[mt][nt][2], 0.f), wo.z, s[nt]);
                s[nt] = fmaf(fmaxf(C[mt][nt][3], 0.f), wo.w, s[nt]);
            }
        }
#pragma unroll
        for (int nt = 0; nt < 4; ++nt) {
            s[nt] += __shfl_xor(s[nt], 16, 64);
            s[nt] += __shfl_xor(s[nt], 32, 64);
        }
        float r = (quad & 1) ? ((quad & 2) ? s[3] : s[1])
                             : ((quad & 2) ? s[2] : s[0]);
        out[wavebase + quad * 16 + l15] = r * (1.f / 8192.f);
    }
}

// =================== FALLBACK: r7 fused kernel (used if ws too small) ========
__global__ __launch_bounds__(TPB, 4) void hashgrid_mlp_kernel(
    const float* __restrict__ x,
    const float* __restrict__ mesh_min,
    const float* __restrict__ mesh_max,
    const float* __restrict__ tables,
    const _Float16* __restrict__ ws,
    const float* __restrict__ w_out,
    float* __restrict__ out,
    int N) {
    __shared__ float2 ltab[881];
    __shared__ _Float16 encbuf[4][64][ENC_ROW];

    const int wave = threadIdx.x >> 6;
    const int lane = threadIdx.x & 63;
    const int l15 = lane & 15;
    const int quad = lane >> 4;
    const int wavebase = blockIdx.x * TPB + wave * 64;
    const int p = wavebase + lane;

    {
        const float2* t0 = (const float2*)tables;
        for (int i = threadIdx.x; i < 27; i += TPB) ltab[i] = t0[i];
        const float2* t1 = (const float2*)(tables + 1 * 524288);
        for (int i = threadIdx.x; i < 125; i += TPB) ltab[27 + i] = t1[i];
        const float2* t2 = (const float2*)(tables + 2 * 524288);
        for (int i = threadIdx.x; i < 729; i += TPB) ltab[152 + i] = t2[i];
    }

    float mn0 = mesh_min[0], mn1 = mesh_min[1], mn2 = mesh_min[2];
    float mx0 = mesh_max[0], mx1 = mesh_max[1], mx2 = mesh_max[2];
    float ux = (x[3 * p + 0] - mn0) / (mx0 - mn0);
    float uy = (x[3 * p + 1] - mn1) / (mx1 - mn1);
    float uz = (x[3 * p + 2] - mn2) / (mx2 - mn2);

    float ef[16];
    float wl[3][3];
    float2 g[24];

#pragma unroll
    for (int l = 0; l < 3; ++l) {
        const int res = 64 << l;
        const float* tab = tables + (size_t)(l + 5) * 524288;
        float px = ux * (float)res, py = uy * (float)res, pz = uz * (float)res;
        int cx = (int)floorf(px), cy = (int)floorf(py), cz = (int)floorf(pz);
        wl[l][0] = px - (float)cx;
        wl[l][1] = py - (float)cy;
        wl[l][2] = pz - (float)cz;
        uint32_t hy0 = (uint32_t)cy * 2654435761u, hy1 = (uint32_t)(cy + 1) * 2654435761u;
        uint32_t hz0 = (uint32_t)cz * 805459861u,  hz1 = (uint32_t)(cz + 1) * 805459861u;
#pragma unroll
        for (int c = 0; c < 4; ++c) {
            uint32_t hyz = ((c & 1) ? hy1 : hy0) ^ ((c & 2) ? hz1 : hz0);
            uint32_t i0 = ((uint32_t)cx ^ hyz) & 262143u;
            uint32_t i1 = ((uint32_t)(cx + 1) ^ hyz) & 262143u;
            g[l * 8 + 2 * c + 0] = *(const float2*)(tab + 2 * (size_t)i0);
            g[l * 8 + 2 * c + 1] = *(const float2*)(tab + 2 * (size_t)i1);
        }
    }

#pragma unroll
    for (int l = 3; l < 5; ++l) {
        const int res = 2 << l;
        const int s = res + 1;
        const float* tab = tables + (size_t)l * 524288;
        float px = ux * (float)res, py = uy * (float)res, pz = uz * (float)res;
        int cx = (int)floorf(px), cy = (int)floorf(py), cz = (int)floorf(pz);
        float wx = px - (float)cx, wy = py - (float)cy, wz = pz - (float)cz;
        float f0 = 0.f, f1 = 0.f;
#pragma unroll
        for (int c = 0; c < 4; ++c) {
            int Y = cy + ((c & 1) ? 1 : 0);
            int Z = cz + ((c & 2) ? 1 : 0);
            float wyz = ((c & 1) ? wy : 1.f - wy) * ((c & 2) ? wz : 1.f - wz);
            int i0 = cx + Y * s + Z * s * s;
            float4u v = *(const float4u*)(tab + 2 * (size_t)i0);
            f0 += wyz * (v.x + wx * (v.z - v.x));
            f1 += wyz * (v.y + wx * (v.w - v.y));
        }
        ef[2 * l + 0] = f0;
        ef[2 * l + 1] = f1;
    }

    __syncthreads();

#pragma unroll
    for (int l = 0; l < 3; ++l) {
        const int res = 2 << l;
        const int s = res + 1;
        const int base = (l == 0) ? 0 : (l == 1) ? 27 : 152;
        float px = ux * (float)res, py = uy * (float)res, pz = uz * (float)res;
        int cx = (int)floorf(px), cy = (int)floorf(py), cz = (int)floorf(pz);
        float wx = px - (float)cx, wy = py - (float)cy, wz = pz - (float)cz;
        float f0 = 0.f, f1 = 0.f;
#pragma unroll
        for (int c = 0; c < 4; ++c) {
            int i0 = base + cx + (cy + ((c & 1) ? 1 : 0)) * s + (cz + ((c & 2) ? 1 : 0)) * s * s;
            float wyz = ((c & 1) ? wy : 1.f - wy) * ((c & 2) ? wz : 1.f - wz);
            float2 e0 = ltab[i0];
            float2 e1 = ltab[i0 + 1];
            f0 += wyz * (e0.x + wx * (e1.x - e0.x));
            f1 += wyz * (e0.y + wx * (e1.y - e0.y));
        }
        ef[2 * l + 0] = f0;
        ef[2 * l + 1] = f1;
    }

#pragma unroll
    for (int l = 0; l < 3; ++l) {
        float wx = wl[l][0], wy = wl[l][1], wz = wl[l][2];
        float f0 = 0.f, f1 = 0.f;
#pragma unroll
        for (int c = 0; c < 4; ++c) {
            float wyz = ((c & 1) ? wy : 1.f - wy) * ((c & 2) ? wz : 1.f - wz);
            float2 e0 = g[l * 8 + 2 * c + 0];
            float2 e1 = g[l * 8 + 2 * c + 1];
            f0 += wyz * (e0.x + wx * (e1.x - e0.x));
            f1 += wyz * (e0.y + wx * (e1.y - e0.y));
        }
        ef[10 + 2 * l + 0] = f0;
        ef[10 + 2 * l + 1] = f1;
    }

#pragma unroll
    for (int v = 0; v < 4; ++v) {
        half2v lo = pkrtz(ef[4 * v + 0] * 8192.f, ef[4 * v + 1] * 8192.f);
        half2v hi = pkrtz(ef[4 * v + 2] * 8192.f, ef[4 * v + 3] * 8192.f);
        half4 t;
        t[0] = lo[0]; t[1] = lo[1]; t[2] = hi[0]; t[3] = hi[1];
        *(half4*)&encbuf[wave][lane][v * 4] = t;
    }

    floatx4 C[4][4];
    {
        half4 b[4];
#pragma unroll
        for (int nt = 0; nt < 4; ++nt)
            b[nt] = *(const half4*)&encbuf[wave][nt * 16 + l15][quad * 4];
#pragma unroll
        for (int mt = 0; mt < 4; ++mt) {
            half4 a = *(const half4*)(ws + mt * 256 + lane * 4);
#pragma unroll
            for (int nt = 0; nt < 4; ++nt) {
                floatx4 zero = {0.f, 0.f, 0.f, 0.f};
                C[mt][nt] = __builtin_amdgcn_mfma_f32_16x16x16f16(a, b[nt], zero, 0, 0, 0);
            }
        }
    }

#pragma unroll
    for (int layer = 0; layer < 3; ++layer) {
        half4 b[4][4];
#pragma unroll
        for (int kt = 0; kt < 4; ++kt)
#pragma unroll
            for (int nt = 0; nt < 4; ++nt)
                b[kt][nt] = relu_pack(C[kt][nt]);
#pragma unroll
        for (int mt = 0; mt < 4; ++mt) {
            half4 a[4];
#pragma unroll
            for (int kt = 0; kt < 4; ++kt)
                a[kt] = *(const half4*)(ws + 1024 + ((layer * 4 + kt) * 4 + mt) * 256 + lane * 4);
#pragma unroll
            for (int nt = 0; nt < 4; ++nt) {
                floatx4 acc = {0.f, 0.f, 0.f, 0.f};
#pragma unroll
                for (int kt = 0; kt < 4; ++kt)
                    acc = __builtin_amdgcn_mfma_f32_16x16x16f16(a[kt], b[kt][nt], acc, 0, 0, 0);
                C[mt][nt] = acc;
            }
        }
    }

    {
        float s[4] = {0.f, 0.f, 0.f, 0.f};
#pragma unroll
        for (int mt = 0; mt < 4; ++mt) {
            float4 wo = *(const float4*)(w_out + mt * 16 + quad * 4);
#pragma unroll
            for (int nt = 0; nt < 4; ++nt) {
                s[nt] = fmaf(fmaxf(C[mt][nt][0], 0.f), wo.x, s[nt]);
                s[nt] = fmaf(fmaxf(C[mt][nt][1], 0.f), wo.y, s[nt]);
                s[nt] = fmaf(fmaxf(C[mt][nt][2], 0.f), wo.z, s[nt]);
                s[nt] = fmaf(fmaxf(C[mt][nt][3], 0.f), wo.w, s[nt]);
            }
        }
#pragma unroll
        for (int nt = 0; nt < 4; ++nt) {
            s[nt] += __shfl_xor(s[nt], 16, 64);
            s[nt] += __shfl_xor(s[nt], 32, 64);
        }
        float r = (quad & 1) ? ((quad & 2) ? s[3] : s[1])
                             : ((quad & 2) ? s[2] : s[0]);
        out[wavebase + quad * 16 + l15] = r * (1.f / 8192.f);
    }
}

extern "C" void kernel_launch(void* const* d_in, const int* in_sizes, int n_in,
                              void* d_out, int out_size, void* d_ws,
                              size_t ws_size, hipStream_t stream) {
    const float* x        = (const float*)d_in[0];
    const float* mesh_min = (const float*)d_in[1];
    const float* mesh_max = (const float*)d_in[2];
    const float* tables   = (const float*)d_in[3];
    const float* w_in     = (const float*)d_in[4];
    const float* w_hidden = (const float*)d_in[5];
    const float* w_out    = (const float*)d_in[6];
    float* out = (float*)d_out;
    _Float16* ws = (_Float16*)d_ws;  // [0..13312): weight frags

    int N = out_size;  // 2,097,152 (multiple of 256)

    // d_ws layout: [0,32KB) weights | [32KB, +8MB) f16 tables
    size_t need = 32768 + (size_t)8 * 262144 * 4;
    if (ws_size >= need) {
        uint32_t* tf = (uint32_t*)((char*)d_ws + 32768);
        hipLaunchKernelGGL(prep_all, dim3(8244), dim3(256), 0, stream,
                           tables, tf, w_in, w_hidden, ws);
        hipLaunchKernelGGL(fused_kernel, dim3(N / TPB), dim3(TPB), 0, stream,
                           x, mesh_min, mesh_max, tables, tf, ws, w_out, out, N);
    } else {
        hipLaunchKernelGGL(prep_weights, dim3(52), dim3(256), 0, stream,
                           w_in, w_hidden, ws);
        hipLaunchKernelGGL(hashgrid_mlp_kernel, dim3(N / TPB), dim3(TPB), 0, stream,
                           x, mesh_min, mesh_max, tables, ws, w_out, out, N);
    }
}

// Round 4
// 269.916 us; speedup vs baseline: 1.9426x; 1.9426x over previous
//
#include <hip/hip_runtime.h>
#include <stdint.h>

typedef _Float16 half2v __attribute__((ext_vector_type(2)));
typedef _Float16 half4 __attribute__((ext_vector_type(4)));
typedef _Float16 half8 __attribute__((ext_vector_type(8)));
typedef float floatx4 __attribute__((ext_vector_type(4)));
typedef float float4u __attribute__((ext_vector_type(4), aligned(8)));

#define TPB 256
#define ENC_ROW 20

__device__ __forceinline__ half2v pkrtz(float a, float b) {
    return __builtin_bit_cast(half2v, __builtin_amdgcn_cvt_pkrtz(a, b));
}

__device__ __forceinline__ half4 relu_pack(floatx4 c) {
    half2v lo = pkrtz(fmaxf(c[0], 0.f), fmaxf(c[1], 0.f));
    half2v hi = pkrtz(fmaxf(c[2], 0.f), fmaxf(c[3], 0.f));
    half4 r;
    r[0] = lo[0]; r[1] = lo[1]; r[2] = hi[0]; r[3] = hi[1];
    return r;
}

// ---------------- combined prep: tables (f16 x 2^13) + weight frags ---------
// Blocks [0,8192): convert 8*262144 float2 table entries to half2 scaled 2^13.
// Blocks [8192,8244): build MFMA A-fragment-ordered f16 weights.
__global__ void prep_all(const float* __restrict__ tables,
                         uint32_t* __restrict__ tf,
                         const float* __restrict__ w_in,
                         const float* __restrict__ w_hidden,
                         _Float16* __restrict__ ws) {
    int b = blockIdx.x;
    if (b < 8192) {
        int i = b * 256 + threadIdx.x;
        float2 v = ((const float2*)tables)[i];
        half2v h;
        h[0] = (_Float16)(v.x * 8192.f);
        h[1] = (_Float16)(v.y * 8192.f);
        tf[i] = __builtin_bit_cast(uint32_t, h);
    } else {
        int i = (b - 8192) * 256 + threadIdx.x;
        if (i < 1024) {
            int j = i & 3, lane = (i >> 2) & 63, mt = i >> 8;
            int k = ((lane >> 4) & 3) * 4 + j;
            int n = mt * 16 + (lane & 15);
            ws[i] = (_Float16)w_in[k * 64 + n];
        } else if (i < 13312) {
            int t = i - 1024;
            int j = t & 3, lane = (t >> 2) & 63;
            int mt = (t >> 8) & 3, kt = (t >> 10) & 3, layer = t >> 12;
            int k = kt * 16 + ((lane >> 4) & 3) * 4 + j;
            int n = mt * 16 + (lane & 15);
            ws[i] = (_Float16)w_hidden[layer * 4096 + k * 64 + n];
        }
    }
}

// ---------------- standalone weight prep (fallback path only) ---------------
__global__ void prep_weights(const float* __restrict__ w_in,
                             const float* __restrict__ w_hidden,
                             _Float16* __restrict__ ws) {
    int i = blockIdx.x * 256 + threadIdx.x;
    if (i < 1024) {
        int j = i & 3, lane = (i >> 2) & 63, mt = i >> 8;
        int k = ((lane >> 4) & 3) * 4 + j;
        int n = mt * 16 + (lane & 15);
        ws[i] = (_Float16)w_in[k * 64 + n];
    } else if (i < 13312) {
        int t = i - 1024;
        int j = t & 3, lane = (t >> 2) & 63;
        int mt = (t >> 8) & 3, kt = (t >> 10) & 3, layer = t >> 12;
        int k = kt * 16 + ((lane >> 4) & 3) * 4 + j;
        int n = mt * 16 + (lane & 15);
        ws[i] = (_Float16)w_hidden[layer * 4096 + k * 64 + n];
    }
}

// =================== FUSED: encode (f16 tables, L0-3 in LDS) + MLP ==========
// r1: fused at 37 KB LDS -> 4 blocks/CU (42%), latency-bound.
// r2: aliased encbuf over table LDS (26.7 KB -> 6 blocks/CU) but
//     __launch_bounds__(256,6) forced a 40-VGPR cap -> g[]/ef[] spilled to
//     scratch (WRITE_SIZE 8->600 MB), dur 214->455 us. LESSON: never constrain
//     the allocator below what the kernel naturally uses (64 VGPR).
// r3/r4: keep the aliasing, restore launch_bounds(256,4). 64 VGPR allows
//     8 waves/SIMD; LDS (27136 B) is now the binding limit at 6 blocks/CU
//     (24 waves, 75%). No allocator pressure, no spill.
//     (r3 bench was an infra failure; this is the same kernel resubmitted.)
__global__ __launch_bounds__(TPB, 4) void fused_kernel(
    const float* __restrict__ x,
    const float* __restrict__ mesh_min,
    const float* __restrict__ mesh_max,
    const float* __restrict__ tables,   // fp32 originals (levels 0-2 LDS build)
    const uint32_t* __restrict__ tabs,  // [8][262144] half2 (scaled by 2^13)
    const _Float16* __restrict__ ws,
    const float* __restrict__ w_out,
    float* __restrict__ out,
    int N) {
    // Phase 1 layout: ltab (881 float2 = 7048 B) | l3tab (4913 u32 = 19652 B)
    // Phase 2 (after barrier): encbuf[4][64][ENC_ROW] f16 = 10240 B, aliased at 0.
    __shared__ __align__(16) char smem[26700];
    float2* ltab = (float2*)smem;
    uint32_t* l3tab = (uint32_t*)(smem + 7048);
    _Float16 (*encbuf)[64][ENC_ROW] = (_Float16 (*)[64][ENC_ROW])smem;

    const int wave = threadIdx.x >> 6;
    const int lane = threadIdx.x & 63;
    const int l15 = lane & 15;
    const int quad = lane >> 4;
    const int wavebase = blockIdx.x * TPB + wave * 64;
    const int p = wavebase + lane;

    // ---- build LDS (coalesced) ----
    {
        const float2* t0 = (const float2*)tables;
        for (int i = threadIdx.x; i < 27; i += TPB) ltab[i] = t0[i];
        const float2* t1 = (const float2*)(tables + 1 * 524288);
        for (int i = threadIdx.x; i < 125; i += TPB) ltab[27 + i] = t1[i];
        const float2* t2 = (const float2*)(tables + 2 * 524288);
        for (int i = threadIdx.x; i < 729; i += TPB) ltab[152 + i] = t2[i];
        const uint32_t* t3 = tabs + 3 * 262144;
        for (int i = threadIdx.x; i < 4913; i += TPB) l3tab[i] = t3[i];
    }

    float mn0 = mesh_min[0], mn1 = mesh_min[1], mn2 = mesh_min[2];
    float mx0 = mesh_max[0], mx1 = mesh_max[1], mx2 = mesh_max[2];
    float ux = (x[3 * p + 0] - mn0) / (mx0 - mn0);
    float uy = (x[3 * p + 1] - mn1) / (mx1 - mn1);
    float uz = (x[3 * p + 2] - mn2) / (mx2 - mn2);

    float ef[16];
    float wl[3][3];
    uint32_t g[24];   // hashed gathers (levels 5-7), issued back-to-back
    uint32_t g4[8];   // level-4 dense gathers
    float w4x, w4y, w4z;

    // ---- hashed levels 5-7: 24 scalar-dword gathers ----
#pragma unroll
    for (int l = 0; l < 3; ++l) {
        const int res = 64 << l;  // 64, 128, 256
        const uint32_t* tab = tabs + (size_t)(l + 5) * 262144;
        float px = ux * (float)res, py = uy * (float)res, pz = uz * (float)res;
        int cx = (int)floorf(px), cy = (int)floorf(py), cz = (int)floorf(pz);
        wl[l][0] = px - (float)cx;
        wl[l][1] = py - (float)cy;
        wl[l][2] = pz - (float)cz;
        uint32_t hy0 = (uint32_t)cy * 2654435761u, hy1 = (uint32_t)(cy + 1) * 2654435761u;
        uint32_t hz0 = (uint32_t)cz * 805459861u,  hz1 = (uint32_t)(cz + 1) * 805459861u;
#pragma unroll
        for (int c = 0; c < 4; ++c) {
            uint32_t hyz = ((c & 1) ? hy1 : hy0) ^ ((c & 2) ? hz1 : hz0);
            uint32_t i0 = ((uint32_t)cx ^ hyz) & 262143u;
            uint32_t i1 = ((uint32_t)(cx + 1) ^ hyz) & 262143u;
            g[l * 8 + 2 * c + 0] = tab[i0];
            g[l * 8 + 2 * c + 1] = tab[i1];
        }
    }

    // ---- dense level 4: 8 scalar-dword gathers, issued now, consumed later ----
    {
        const int s = 33;
        const uint32_t* tab = tabs + (size_t)4 * 262144;
        float px = ux * 32.f, py = uy * 32.f, pz = uz * 32.f;
        int cx = (int)floorf(px), cy = (int)floorf(py), cz = (int)floorf(pz);
        w4x = px - (float)cx; w4y = py - (float)cy; w4z = pz - (float)cz;
#pragma unroll
        for (int c = 0; c < 4; ++c) {
            int Y = cy + ((c & 1) ? 1 : 0);
            int Z = cz + ((c & 2) ? 1 : 0);
            int i0 = cx + Y * s + Z * s * s;
            g4[2 * c + 0] = tab[i0];
            g4[2 * c + 1] = tab[i0 + 1];
        }
    }

    __syncthreads();  // LDS tables ready; in-flight global gathers keep draining

    // ---- levels 0-2 from LDS (fp32), scale to match f16 tables ----
#pragma unroll
    for (int l = 0; l < 3; ++l) {
        const int res = 2 << l;
        const int s = res + 1;
        const int base = (l == 0) ? 0 : (l == 1) ? 27 : 152;
        float px = ux * (float)res, py = uy * (float)res, pz = uz * (float)res;
        int cx = (int)floorf(px), cy = (int)floorf(py), cz = (int)floorf(pz);
        float wx = px - (float)cx, wy = py - (float)cy, wz = pz - (float)cz;
        float f0 = 0.f, f1 = 0.f;
#pragma unroll
        for (int c = 0; c < 4; ++c) {
            int i0 = base + cx + (cy + ((c & 1) ? 1 : 0)) * s + (cz + ((c & 2) ? 1 : 0)) * s * s;
            float wyz = ((c & 1) ? wy : 1.f - wy) * ((c & 2) ? wz : 1.f - wz);
            float2 e0 = ltab[i0];
            float2 e1 = ltab[i0 + 1];
            f0 += wyz * (e0.x + wx * (e1.x - e0.x));
            f1 += wyz * (e0.y + wx * (e1.y - e0.y));
        }
        ef[2 * l + 0] = f0 * 8192.f;
        ef[2 * l + 1] = f1 * 8192.f;
    }

    // ---- level 3 from LDS (half2, pre-scaled) ----
    {
        const int s = 17;
        float px = ux * 16.f, py = uy * 16.f, pz = uz * 16.f;
        int cx = (int)floorf(px), cy = (int)floorf(py), cz = (int)floorf(pz);
        float wx = px - (float)cx, wy = py - (float)cy, wz = pz - (float)cz;
        float f0 = 0.f, f1 = 0.f;
#pragma unroll
        for (int c = 0; c < 4; ++c) {
            int i0 = cx + (cy + ((c & 1) ? 1 : 0)) * s + (cz + ((c & 2) ? 1 : 0)) * s * s;
            float wyz = ((c & 1) ? wy : 1.f - wy) * ((c & 2) ? wz : 1.f - wz);
            half2v e0 = __builtin_bit_cast(half2v, l3tab[i0]);
            half2v e1 = __builtin_bit_cast(half2v, l3tab[i0 + 1]);
            f0 += wyz * ((float)e0[0] + wx * ((float)e1[0] - (float)e0[0]));
            f1 += wyz * ((float)e0[1] + wx * ((float)e1[1] - (float)e0[1]));
        }
        ef[6] = f0;
        ef[7] = f1;
    }

    // ---- level 4 from buffered gathers ----
    {
        float f0 = 0.f, f1 = 0.f;
#pragma unroll
        for (int c = 0; c < 4; ++c) {
            float wyz = ((c & 1) ? w4y : 1.f - w4y) * ((c & 2) ? w4z : 1.f - w4z);
            half2v e0 = __builtin_bit_cast(half2v, g4[2 * c + 0]);
            half2v e1 = __builtin_bit_cast(half2v, g4[2 * c + 1]);
            f0 += wyz * ((float)e0[0] + w4x * ((float)e1[0] - (float)e0[0]));
            f1 += wyz * ((float)e0[1] + w4x * ((float)e1[1] - (float)e0[1]));
        }
        ef[8] = f0;
        ef[9] = f1;
    }

    // ---- hashed levels 5-7 ----
#pragma unroll
    for (int l = 0; l < 3; ++l) {
        float wx = wl[l][0], wy = wl[l][1], wz = wl[l][2];
        float f0 = 0.f, f1 = 0.f;
#pragma unroll
        for (int c = 0; c < 4; ++c) {
            float wyz = ((c & 1) ? wy : 1.f - wy) * ((c & 2) ? wz : 1.f - wz);
            half2v e0 = __builtin_bit_cast(half2v, g[l * 8 + 2 * c + 0]);
            half2v e1 = __builtin_bit_cast(half2v, g[l * 8 + 2 * c + 1]);
            f0 += wyz * ((float)e0[0] + wx * ((float)e1[0] - (float)e0[0]));
            f1 += wyz * ((float)e0[1] + wx * ((float)e1[1] - (float)e0[1]));
        }
        ef[10 + 2 * l + 0] = f0;
        ef[10 + 2 * l + 1] = f1;
    }

    // ---- barrier: all table reads done, safe to alias encbuf over tables ----
    __syncthreads();

    // ---- pack to per-wave LDS staging (wave-synchronous) ----
#pragma unroll
    for (int v = 0; v < 4; ++v) {
        half2v lo = pkrtz(ef[4 * v + 0], ef[4 * v + 1]);
        half2v hi = pkrtz(ef[4 * v + 2], ef[4 * v + 3]);
        half4 t;
        t[0] = lo[0]; t[1] = lo[1]; t[2] = hi[0]; t[3] = hi[1];
        *(half4*)&encbuf[wave][lane][v * 4] = t;
    }

    // ---- MLP layer 1: enc(16) -> 64, D = Win^T * Enc^T ----
    floatx4 C[4][4];
    {
        half4 b[4];
#pragma unroll
        for (int nt = 0; nt < 4; ++nt)
            b[nt] = *(const half4*)&encbuf[wave][nt * 16 + l15][quad * 4];
#pragma unroll
        for (int mt = 0; mt < 4; ++mt) {
            half4 a = *(const half4*)(ws + mt * 256 + lane * 4);
#pragma unroll
            for (int nt = 0; nt < 4; ++nt) {
                floatx4 zero = {0.f, 0.f, 0.f, 0.f};
                C[mt][nt] = __builtin_amdgcn_mfma_f32_16x16x16f16(a, b[nt], zero, 0, 0, 0);
            }
        }
    }

    // ---- layers 2..4: 64 -> 64; C regs (relu+pack) ARE the next B-frags ----
#pragma unroll
    for (int layer = 0; layer < 3; ++layer) {
        half4 b[4][4];  // [kt][nt]
#pragma unroll
        for (int kt = 0; kt < 4; ++kt)
#pragma unroll
            for (int nt = 0; nt < 4; ++nt)
                b[kt][nt] = relu_pack(C[kt][nt]);
#pragma unroll
        for (int mt = 0; mt < 4; ++mt) {
            half4 a[4];
#pragma unroll
            for (int kt = 0; kt < 4; ++kt)
                a[kt] = *(const half4*)(ws + 1024 + ((layer * 4 + kt) * 4 + mt) * 256 + lane * 4);
#pragma unroll
            for (int nt = 0; nt < 4; ++nt) {
                floatx4 acc = {0.f, 0.f, 0.f, 0.f};
#pragma unroll
                for (int kt = 0; kt < 4; ++kt)
                    acc = __builtin_amdgcn_mfma_f32_16x16x16f16(a[kt], b[kt][nt], acc, 0, 0, 0);
                C[mt][nt] = acc;
            }
        }
    }

    // ---- output layer: relu(h4) . w_out, quad-reduce, unscale ----
    {
        float s[4] = {0.f, 0.f, 0.f, 0.f};
#pragma unroll
        for (int mt = 0; mt < 4; ++mt) {
            float4 wo = *(const float4*)(w_out + mt * 16 + quad * 4);
#pragma unroll
            for (int nt = 0; nt < 4; ++nt) {
                s[nt] = fmaf(fmaxf(C[mt][nt][0], 0.f), wo.x, s[nt]);
                s[nt] = fmaf(fmaxf(C[mt][nt][1], 0.f), wo.y, s[nt]);
                s[nt] = fmaf(fmaxf(C[mt][nt][2], 0.f), wo.z, s[nt]);
                s[nt] = fmaf(fmaxf(C[mt][nt][3], 0.f), wo.w, s[nt]);
            }
        }
#pragma unroll
        for (int nt = 0; nt < 4; ++nt) {
            s[nt] += __shfl_xor(s[nt], 16, 64);
            s[nt] += __shfl_xor(s[nt], 32, 64);
        }
        float r = (quad & 1) ? ((quad & 2) ? s[3] : s[1])
                             : ((quad & 2) ? s[2] : s[0]);
        out[wavebase + quad * 16 + l15] = r * (1.f / 8192.f);
    }
}

// =================== FALLBACK: r7 fused kernel (used if ws too small) ========
__global__ __launch_bounds__(TPB, 4) void hashgrid_mlp_kernel(
    const float* __restrict__ x,
    const float* __restrict__ mesh_min,
    const float* __restrict__ mesh_max,
    const float* __restrict__ tables,
    const _Float16* __restrict__ ws,
    const float* __restrict__ w_out,
    float* __restrict__ out,
    int N) {
    __shared__ float2 ltab[881];
    __shared__ _Float16 encbuf[4][64][ENC_ROW];

    const int wave = threadIdx.x >> 6;
    const int lane = threadIdx.x & 63;
    const int l15 = lane & 15;
    const int quad = lane >> 4;
    const int wavebase = blockIdx.x * TPB + wave * 64;
    const int p = wavebase + lane;

    {
        const float2* t0 = (const float2*)tables;
        for (int i = threadIdx.x; i < 27; i += TPB) ltab[i] = t0[i];
        const float2* t1 = (const float2*)(tables + 1 * 524288);
        for (int i = threadIdx.x; i < 125; i += TPB) ltab[27 + i] = t1[i];
        const float2* t2 = (const float2*)(tables + 2 * 524288);
        for (int i = threadIdx.x; i < 729; i += TPB) ltab[152 + i] = t2[i];
    }

    float mn0 = mesh_min[0], mn1 = mesh_min[1], mn2 = mesh_min[2];
    float mx0 = mesh_max[0], mx1 = mesh_max[1], mx2 = mesh_max[2];
    float ux = (x[3 * p + 0] - mn0) / (mx0 - mn0);
    float uy = (x[3 * p + 1] - mn1) / (mx1 - mn1);
    float uz = (x[3 * p + 2] - mn2) / (mx2 - mn2);

    float ef[16];
    float wl[3][3];
    float2 g[24];

#pragma unroll
    for (int l = 0; l < 3; ++l) {
        const int res = 64 << l;
        const float* tab = tables + (size_t)(l + 5) * 524288;
        float px = ux * (float)res, py = uy * (float)res, pz = uz * (float)res;
        int cx = (int)floorf(px), cy = (int)floorf(py), cz = (int)floorf(pz);
        wl[l][0] = px - (float)cx;
        wl[l][1] = py - (float)cy;
        wl[l][2] = pz - (float)cz;
        uint32_t hy0 = (uint32_t)cy * 2654435761u, hy1 = (uint32_t)(cy + 1) * 2654435761u;
        uint32_t hz0 = (uint32_t)cz * 805459861u,  hz1 = (uint32_t)(cz + 1) * 805459861u;
#pragma unroll
        for (int c = 0; c < 4; ++c) {
            uint32_t hyz = ((c & 1) ? hy1 : hy0) ^ ((c & 2) ? hz1 : hz0);
            uint32_t i0 = ((uint32_t)cx ^ hyz) & 262143u;
            uint32_t i1 = ((uint32_t)(cx + 1) ^ hyz) & 262143u;
            g[l * 8 + 2 * c + 0] = *(const float2*)(tab + 2 * (size_t)i0);
            g[l * 8 + 2 * c + 1] = *(const float2*)(tab + 2 * (size_t)i1);
        }
    }

#pragma unroll
    for (int l = 3; l < 5; ++l) {
        const int res = 2 << l;
        const int s = res + 1;
        const float* tab = tables + (size_t)l * 524288;
        float px = ux * (float)res, py = uy * (float)res, pz = uz * (float)res;
        int cx = (int)floorf(px), cy = (int)floorf(py), cz = (int)floorf(pz);
        float wx = px - (float)cx, wy = py - (float)cy, wz = pz - (float)cz;
        float f0 = 0.f, f1 = 0.f;
#pragma unroll
        for (int c = 0; c < 4; ++c) {
            int Y = cy + ((c & 1) ? 1 : 0);
            int Z = cz + ((c & 2) ? 1 : 0);
            float wyz = ((c & 1) ? wy : 1.f - wy) * ((c & 2) ? wz : 1.f - wz);
            int i0 = cx + Y * s + Z * s * s;
            float4u v = *(const float4u*)(tab + 2 * (size_t)i0);
            f0 += wyz * (v.x + wx * (v.z - v.x));
            f1 += wyz * (v.y + wx * (v.w - v.y));
        }
        ef[2 * l + 0] = f0;
        ef[2 * l + 1] = f1;
    }

    __syncthreads();

#pragma unroll
    for (int l = 0; l < 3; ++l) {
        const int res = 2 << l;
        const int s = res + 1;
        const int base = (l == 0) ? 0 : (l == 1) ? 27 : 152;
        float px = ux * (float)res, py = uy * (float)res, pz = uz * (float)res;
        int cx = (int)floorf(px), cy = (int)floorf(py), cz = (int)floorf(pz);
        float wx = px - (float)cx, wy = py - (float)cy, wz = pz - (float)cz;
        float f0 = 0.f, f1 = 0.f;
#pragma unroll
        for (int c = 0; c < 4; ++c) {
            int i0 = base + cx + (cy + ((c & 1) ? 1 : 0)) * s + (cz + ((c & 2) ? 1 : 0)) * s * s;
            float wyz = ((c & 1) ? wy : 1.f - wy) * ((c & 2) ? wz : 1.f - wz);
            float2 e0 = ltab[i0];
            float2 e1 = ltab[i0 + 1];
            f0 += wyz * (e0.x + wx * (e1.x - e0.x));
            f1 += wyz * (e0.y + wx * (e1.y - e0.y));
        }
        ef[2 * l + 0] = f0;
        ef[2 * l + 1] = f1;
    }

#pragma unroll
    for (int l = 0; l < 3; ++l) {
        float wx = wl[l][0], wy = wl[l][1], wz = wl[l][2];
        float f0 = 0.f, f1 = 0.f;
#pragma unroll
        for (int c = 0; c < 4; ++c) {
            float wyz = ((c & 1) ? wy : 1.f - wy) * ((c & 2) ? wz : 1.f - wz);
            float2 e0 = g[l * 8 + 2 * c + 0];
            float2 e1 = g[l * 8 + 2 * c + 1];
            f0 += wyz * (e0.x + wx * (e1.x - e0.x));
            f1 += wyz * (e0.y + wx * (e1.y - e0.y));
        }
        ef[10 + 2 * l + 0] = f0;
        ef[10 + 2 * l + 1] = f1;
    }

#pragma unroll
    for (int v = 0; v < 4; ++v) {
        half2v lo = pkrtz(ef[4 * v + 0] * 8192.f, ef[4 * v + 1] * 8192.f);
        half2v hi = pkrtz(ef[4 * v + 2] * 8192.f, ef[4 * v + 3] * 8192.f);
        half4 t;
        t[0] = lo[0]; t[1] = lo[1]; t[2] = hi[0]; t[3] = hi[1];
        *(half4*)&encbuf[wave][lane][v * 4] = t;
    }

    floatx4 C[4][4];
    {
        half4 b[4];
#pragma unroll
        for (int nt = 0; nt < 4; ++nt)
            b[nt] = *(const half4*)&encbuf[wave][nt * 16 + l15][quad * 4];
#pragma unroll
        for (int mt = 0; mt < 4; ++mt) {
            half4 a = *(const half4*)(ws + mt * 256 + lane * 4);
#pragma unroll
            for (int nt = 0; nt < 4; ++nt) {
                floatx4 zero = {0.f, 0.f, 0.f, 0.f};
                C[mt][nt] = __builtin_amdgcn_mfma_f32_16x16x16f16(a, b[nt], zero, 0, 0, 0);
            }
        }
    }

#pragma unroll
    for (int layer = 0; layer < 3; ++layer) {
        half4 b[4][4];
#pragma unroll
        for (int kt = 0; kt < 4; ++kt)
#pragma unroll
            for (int nt = 0; nt < 4; ++nt)
                b[kt][nt] = relu_pack(C[kt][nt]);
#pragma unroll
        for (int mt = 0; mt < 4; ++mt) {
            half4 a[4];
#pragma unroll
            for (int kt = 0; kt < 4; ++kt)
                a[kt] = *(const half4*)(ws + 1024 + ((layer * 4 + kt) * 4 + mt) * 256 + lane * 4);
#pragma unroll
            for (int nt = 0; nt < 4; ++nt) {
                floatx4 acc = {0.f, 0.f, 0.f, 0.f};
#pragma unroll
                for (int kt = 0; kt < 4; ++kt)
                    acc = __builtin_amdgcn_mfma_f32_16x16x16f16(a[kt], b[kt][nt], acc, 0, 0, 0);
                C[mt][nt] = acc;
            }
        }
    }

    {
        float s[4] = {0.f, 0.f, 0.f, 0.f};
#pragma unroll
        for (int mt = 0; mt < 4; ++mt) {
            float4 wo = *(const float4*)(w_out + mt * 16 + quad * 4);
#pragma unroll
            for (int nt = 0; nt < 4; ++nt) {
                s[nt] = fmaf(fmaxf(C[mt][nt][0], 0.f), wo.x, s[nt]);
                s[nt] = fmaf(fmaxf(C[mt][nt][1], 0.f), wo.y, s[nt]);
                s[nt] = fmaf(fmaxf(C[mt][nt][2], 0.f), wo.z, s[nt]);
                s[nt] = fmaf(fmaxf(C[mt][nt][3], 0.f), wo.w, s[nt]);
            }
        }
#pragma unroll
        for (int nt = 0; nt < 4; ++nt) {
            s[nt] += __shfl_xor(s[nt], 16, 64);
            s[nt] += __shfl_xor(s[nt], 32, 64);
        }
        float r = (quad & 1) ? ((quad & 2) ? s[3] : s[1])
                             : ((quad & 2) ? s[2] : s[0]);
        out[wavebase + quad * 16 + l15] = r * (1.f / 8192.f);
    }
}

extern "C" void kernel_launch(void* const* d_in, const int* in_sizes, int n_in,
                              void* d_out, int out_size, void* d_ws,
                              size_t ws_size, hipStream_t stream) {
    const float* x        = (const float*)d_in[0];
    const float* mesh_min = (const float*)d_in[1];
    const float* mesh_max = (const float*)d_in[2];
    const float* tables   = (const float*)d_in[3];
    const float* w_in     = (const float*)d_in[4];
    const float* w_hidden = (const float*)d_in[5];
    const float* w_out    = (const float*)d_in[6];
    float* out = (float*)d_out;
    _Float16* ws = (_Float16*)d_ws;  // [0..13312): weight frags

    int N = out_size;  // 2,097,152 (multiple of 256)

    // d_ws layout: [0,32KB) weights | [32KB, +8MB) f16 tables
    size_t need = 32768 + (size_t)8 * 262144 * 4;
    if (ws_size >= need) {
        uint32_t* tf = (uint32_t*)((char*)d_ws + 32768);
        hipLaunchKernelGGL(prep_all, dim3(8244), dim3(256), 0, stream,
                           tables, tf, w_in, w_hidden, ws);
        hipLaunchKernelGGL(fused_kernel, dim3(N / TPB), dim3(TPB), 0, stream,
                           x, mesh_min, mesh_max, tables, tf, ws, w_out, out, N);
    } else {
        hipLaunchKernelGGL(prep_weights, dim3(52), dim3(256), 0, stream,
                           w_in, w_hidden, ws);
        hipLaunchKernelGGL(hashgrid_mlp_kernel, dim3(N / TPB), dim3(TPB), 0, stream,
                           x, mesh_min, mesh_max, tables, ws, w_out, out, N);
    }
}

// Round 5
// 268.135 us; speedup vs baseline: 1.9555x; 1.0066x over previous
//
#include <hip/hip_runtime.h>
#include <stdint.h>

typedef _Float16 half2v __attribute__((ext_vector_type(2)));
typedef _Float16 half4 __attribute__((ext_vector_type(4)));
typedef float floatx4 __attribute__((ext_vector_type(4)));
typedef float float4u __attribute__((ext_vector_type(4), aligned(8)));

#define TPB 256
#define ENC_ROW 20

__device__ __forceinline__ uint32_t pkrtz_u32(float a, float b) {
    return __builtin_bit_cast(uint32_t, __builtin_amdgcn_cvt_pkrtz(a, b));
}
__device__ __forceinline__ half2v pkrtz(float a, float b) {
    return __builtin_bit_cast(half2v, __builtin_amdgcn_cvt_pkrtz(a, b));
}

__device__ __forceinline__ half4 relu_pack(floatx4 c) {
    half2v lo = pkrtz(fmaxf(c[0], 0.f), fmaxf(c[1], 0.f));
    half2v hi = pkrtz(fmaxf(c[2], 0.f), fmaxf(c[3], 0.f));
    half4 r;
    r[0] = lo[0]; r[1] = lo[1]; r[2] = hi[0]; r[3] = hi[1];
    return r;
}

// ---------------- combined prep: tables (f16 x 2^13) + weight frags ---------
__global__ void prep_all(const float* __restrict__ tables,
                         uint32_t* __restrict__ tf,
                         const float* __restrict__ w_in,
                         const float* __restrict__ w_hidden,
                         _Float16* __restrict__ ws) {
    int b = blockIdx.x;
    if (b < 8192) {
        int i = b * 256 + threadIdx.x;
        float2 v = ((const float2*)tables)[i];
        tf[i] = pkrtz_u32(v.x * 8192.f, v.y * 8192.f);
    } else {
        int i = (b - 8192) * 256 + threadIdx.x;
        if (i < 1024) {
            int j = i & 3, lane = (i >> 2) & 63, mt = i >> 8;
            int k = ((lane >> 4) & 3) * 4 + j;
            int n = mt * 16 + (lane & 15);
            ws[i] = (_Float16)w_in[k * 64 + n];
        } else if (i < 13312) {
            int t = i - 1024;
            int j = t & 3, lane = (t >> 2) & 63;
            int mt = (t >> 8) & 3, kt = (t >> 10) & 3, layer = t >> 12;
            int k = kt * 16 + ((lane >> 4) & 3) * 4 + j;
            int n = mt * 16 + (lane & 15);
            ws[i] = (_Float16)w_hidden[layer * 4096 + k * 64 + n];
        }
    }
}

// ---------------- standalone weight prep (fallback path only) ---------------
__global__ void prep_weights(const float* __restrict__ w_in,
                             const float* __restrict__ w_hidden,
                             _Float16* __restrict__ ws) {
    int i = blockIdx.x * 256 + threadIdx.x;
    if (i < 1024) {
        int j = i & 3, lane = (i >> 2) & 63, mt = i >> 8;
        int k = ((lane >> 4) & 3) * 4 + j;
        int n = mt * 16 + (lane & 15);
        ws[i] = (_Float16)w_in[k * 64 + n];
    } else if (i < 13312) {
        int t = i - 1024;
        int j = t & 3, lane = (t >> 2) & 63;
        int mt = (t >> 8) & 3, kt = (t >> 10) & 3, layer = t >> 12;
        int k = kt * 16 + ((lane >> 4) & 3) * 4 + j;
        int n = mt * 16 + (lane & 15);
        ws[i] = (_Float16)w_hidden[layer * 4096 + k * 64 + n];
    }
}

// =================== FUSED: encode (f16 tables, L0-3 in LDS) + MLP ==========
// r1: 37 KB LDS -> 4 blocks/CU (42%), latency-bound.
// r2: launch_bounds(256,6) VGPR-capped at 40 -> scratch spill, 455 us.
// r4: LDS aliasing to 27 KB did NOT raise occupancy (43% = r1's 42%):
//     the true limiter is the unified VGPR+accum footprint (~64 arch +
//     64 accum for C[4][4] = ~128/wave -> 4 waves/SIMD).
// r5: halve the accumulator live set: MLP in TWO passes of 2 point-tiles
//     (C[4][2] = 32 accum). Encode side: pack ef to u32 halves per level
//     (8 u32 not 16 f32) and recompute trilinear fractions at consume time
//     (drop wl[9]/w4[3]). Target <=~85 regs -> 6 waves/SIMD, matching the
//     6-block LDS limit (24 waves, 75%).
__global__ __launch_bounds__(TPB, 4) void fused_kernel(
    const float* __restrict__ x,
    const float* __restrict__ mesh_min,
    const float* __restrict__ mesh_max,
    const float* __restrict__ tables,   // fp32 originals (levels 0-2 LDS build)
    const uint32_t* __restrict__ tabs,  // [8][262144] half2 (scaled by 2^13)
    const _Float16* __restrict__ ws,
    const float* __restrict__ w_out,
    float* __restrict__ out,
    int N) {
    // Phase 1 layout: ltab (881 float2 = 7048 B) | l3tab (4913 u32 = 19652 B)
    // Phase 2 (after barrier 2): encbuf[4][64][ENC_ROW] f16 = 10240 B, aliased.
    __shared__ __align__(16) char smem[26700];
    float2* ltab = (float2*)smem;
    uint32_t* l3tab = (uint32_t*)(smem + 7048);
    _Float16 (*encbuf)[64][ENC_ROW] = (_Float16 (*)[64][ENC_ROW])smem;

    const int wave = threadIdx.x >> 6;
    const int lane = threadIdx.x & 63;
    const int l15 = lane & 15;
    const int quad = lane >> 4;
    const int wavebase = blockIdx.x * TPB + wave * 64;
    const int p = wavebase + lane;

    // ---- build LDS (coalesced) ----
    {
        const float2* t0 = (const float2*)tables;
        for (int i = threadIdx.x; i < 27; i += TPB) ltab[i] = t0[i];
        const float2* t1 = (const float2*)(tables + 1 * 524288);
        for (int i = threadIdx.x; i < 125; i += TPB) ltab[27 + i] = t1[i];
        const float2* t2 = (const float2*)(tables + 2 * 524288);
        for (int i = threadIdx.x; i < 729; i += TPB) ltab[152 + i] = t2[i];
        const uint32_t* t3 = tabs + 3 * 262144;
        for (int i = threadIdx.x; i < 4913; i += TPB) l3tab[i] = t3[i];
    }

    float mn0 = mesh_min[0], mn1 = mesh_min[1], mn2 = mesh_min[2];
    float mx0 = mesh_max[0], mx1 = mesh_max[1], mx2 = mesh_max[2];
    float ux = (x[3 * p + 0] - mn0) / (mx0 - mn0);
    float uy = (x[3 * p + 1] - mn1) / (mx1 - mn1);
    float uz = (x[3 * p + 2] - mn2) / (mx2 - mn2);

    uint32_t e[8];    // packed half2 features per level
    uint32_t g[24];   // hashed gathers (levels 5-7), issued back-to-back
    uint32_t g4[8];   // level-4 dense gathers

    // ---- hashed levels 5-7: 24 scalar-dword gathers (issue only) ----
#pragma unroll
    for (int l = 0; l < 3; ++l) {
        const int res = 64 << l;  // 64, 128, 256
        const uint32_t* tab = tabs + (size_t)(l + 5) * 262144;
        int cx = (int)floorf(ux * (float)res);
        int cy = (int)floorf(uy * (float)res);
        int cz = (int)floorf(uz * (float)res);
        uint32_t hy0 = (uint32_t)cy * 2654435761u, hy1 = (uint32_t)(cy + 1) * 2654435761u;
        uint32_t hz0 = (uint32_t)cz * 805459861u,  hz1 = (uint32_t)(cz + 1) * 805459861u;
#pragma unroll
        for (int c = 0; c < 4; ++c) {
            uint32_t hyz = ((c & 1) ? hy1 : hy0) ^ ((c & 2) ? hz1 : hz0);
            uint32_t i0 = ((uint32_t)cx ^ hyz) & 262143u;
            uint32_t i1 = ((uint32_t)(cx + 1) ^ hyz) & 262143u;
            g[l * 8 + 2 * c + 0] = tab[i0];
            g[l * 8 + 2 * c + 1] = tab[i1];
        }
    }

    // ---- dense level 4: 8 scalar-dword gathers (issue only) ----
    {
        const int s = 33;
        const uint32_t* tab = tabs + (size_t)4 * 262144;
        int cx = (int)floorf(ux * 32.f);
        int cy = (int)floorf(uy * 32.f);
        int cz = (int)floorf(uz * 32.f);
#pragma unroll
        for (int c = 0; c < 4; ++c) {
            int Y = cy + ((c & 1) ? 1 : 0);
            int Z = cz + ((c & 2) ? 1 : 0);
            int i0 = cx + Y * s + Z * s * s;
            g4[2 * c + 0] = tab[i0];
            g4[2 * c + 1] = tab[i0 + 1];
        }
    }

    __syncthreads();  // LDS tables ready; in-flight global gathers keep draining

    // ---- levels 0-2 from LDS (fp32), scale to match f16 tables ----
#pragma unroll
    for (int l = 0; l < 3; ++l) {
        const int res = 2 << l;
        const int s = res + 1;
        const int base = (l == 0) ? 0 : (l == 1) ? 27 : 152;
        float px = ux * (float)res, py = uy * (float)res, pz = uz * (float)res;
        int cx = (int)floorf(px), cy = (int)floorf(py), cz = (int)floorf(pz);
        float wx = px - (float)cx, wy = py - (float)cy, wz = pz - (float)cz;
        float f0 = 0.f, f1 = 0.f;
#pragma unroll
        for (int c = 0; c < 4; ++c) {
            int i0 = base + cx + (cy + ((c & 1) ? 1 : 0)) * s + (cz + ((c & 2) ? 1 : 0)) * s * s;
            float wyz = ((c & 1) ? wy : 1.f - wy) * ((c & 2) ? wz : 1.f - wz);
            float2 e0 = ltab[i0];
            float2 e1 = ltab[i0 + 1];
            f0 += wyz * (e0.x + wx * (e1.x - e0.x));
            f1 += wyz * (e0.y + wx * (e1.y - e0.y));
        }
        e[l] = pkrtz_u32(f0 * 8192.f, f1 * 8192.f);
    }

    // ---- level 3 from LDS (half2, pre-scaled) ----
    {
        const int s = 17;
        float px = ux * 16.f, py = uy * 16.f, pz = uz * 16.f;
        int cx = (int)floorf(px), cy = (int)floorf(py), cz = (int)floorf(pz);
        float wx = px - (float)cx, wy = py - (float)cy, wz = pz - (float)cz;
        float f0 = 0.f, f1 = 0.f;
#pragma unroll
        for (int c = 0; c < 4; ++c) {
            int i0 = cx + (cy + ((c & 1) ? 1 : 0)) * s + (cz + ((c & 2) ? 1 : 0)) * s * s;
            float wyz = ((c & 1) ? wy : 1.f - wy) * ((c & 2) ? wz : 1.f - wz);
            half2v e0 = __builtin_bit_cast(half2v, l3tab[i0]);
            half2v e1 = __builtin_bit_cast(half2v, l3tab[i0 + 1]);
            f0 += wyz * ((float)e0[0] + wx * ((float)e1[0] - (float)e0[0]));
            f1 += wyz * ((float)e0[1] + wx * ((float)e1[1] - (float)e0[1]));
        }
        e[3] = pkrtz_u32(f0, f1);
    }

    // ---- level 4 from buffered gathers (fractions recomputed) ----
    {
        float wx = ux * 32.f; wx -= floorf(wx);
        float wy = uy * 32.f; wy -= floorf(wy);
        float wz = uz * 32.f; wz -= floorf(wz);
        float f0 = 0.f, f1 = 0.f;
#pragma unroll
        for (int c = 0; c < 4; ++c) {
            float wyz = ((c & 1) ? wy : 1.f - wy) * ((c & 2) ? wz : 1.f - wz);
            half2v e0 = __builtin_bit_cast(half2v, g4[2 * c + 0]);
            half2v e1 = __builtin_bit_cast(half2v, g4[2 * c + 1]);
            f0 += wyz * ((float)e0[0] + wx * ((float)e1[0] - (float)e0[0]));
            f1 += wyz * ((float)e0[1] + wx * ((float)e1[1] - (float)e0[1]));
        }
        e[4] = pkrtz_u32(f0, f1);
    }

    // ---- hashed levels 5-7 (fractions recomputed) ----
#pragma unroll
    for (int l = 0; l < 3; ++l) {
        const float res = (float)(64 << l);
        float wx = ux * res; wx -= floorf(wx);
        float wy = uy * res; wy -= floorf(wy);
        float wz = uz * res; wz -= floorf(wz);
        float f0 = 0.f, f1 = 0.f;
#pragma unroll
        for (int c = 0; c < 4; ++c) {
            float wyz = ((c & 1) ? wy : 1.f - wy) * ((c & 2) ? wz : 1.f - wz);
            half2v e0 = __builtin_bit_cast(half2v, g[l * 8 + 2 * c + 0]);
            half2v e1 = __builtin_bit_cast(half2v, g[l * 8 + 2 * c + 1]);
            f0 += wyz * ((float)e0[0] + wx * ((float)e1[0] - (float)e0[0]));
            f1 += wyz * ((float)e0[1] + wx * ((float)e1[1] - (float)e0[1]));
        }
        e[5 + l] = pkrtz_u32(f0, f1);
    }

    // ---- barrier: all table reads done, safe to alias encbuf over tables ----
    __syncthreads();

    // ---- store packed features to per-wave LDS staging (wave-synchronous) ----
    {
        _Float16* row = &encbuf[wave][lane][0];
        uint2* r2 = (uint2*)row;
        uint2 t;
        t.x = e[0]; t.y = e[1]; r2[0] = t;
        t.x = e[2]; t.y = e[3]; r2[1] = t;
        t.x = e[4]; t.y = e[5]; r2[2] = t;
        t.x = e[6]; t.y = e[7]; r2[3] = t;
    }

    // ---- MLP in two passes of 2 point-tiles (C[4][2] = 32 accum regs) ----
    float sacc[4];
#pragma unroll
    for (int h = 0; h < 2; ++h) {
        floatx4 C[4][2];
        // layer 1: enc(16) -> 64, D = Win^T * Enc^T
        {
            half4 b0 = *(const half4*)&encbuf[wave][(2 * h + 0) * 16 + l15][quad * 4];
            half4 b1 = *(const half4*)&encbuf[wave][(2 * h + 1) * 16 + l15][quad * 4];
#pragma unroll
            for (int mt = 0; mt < 4; ++mt) {
                half4 a = *(const half4*)(ws + mt * 256 + lane * 4);
                floatx4 zero = {0.f, 0.f, 0.f, 0.f};
                C[mt][0] = __builtin_amdgcn_mfma_f32_16x16x16f16(a, b0, zero, 0, 0, 0);
                C[mt][1] = __builtin_amdgcn_mfma_f32_16x16x16f16(a, b1, zero, 0, 0, 0);
            }
        }
        // layers 2..4: 64 -> 64
#pragma unroll
        for (int layer = 0; layer < 3; ++layer) {
            half4 b[4][2];
#pragma unroll
            for (int kt = 0; kt < 4; ++kt) {
                b[kt][0] = relu_pack(C[kt][0]);
                b[kt][1] = relu_pack(C[kt][1]);
            }
#pragma unroll
            for (int mt = 0; mt < 4; ++mt) {
                half4 a[4];
#pragma unroll
                for (int kt = 0; kt < 4; ++kt)
                    a[kt] = *(const half4*)(ws + 1024 + ((layer * 4 + kt) * 4 + mt) * 256 + lane * 4);
#pragma unroll
                for (int j = 0; j < 2; ++j) {
                    floatx4 acc = {0.f, 0.f, 0.f, 0.f};
#pragma unroll
                    for (int kt = 0; kt < 4; ++kt)
                        acc = __builtin_amdgcn_mfma_f32_16x16x16f16(a[kt], b[kt][j], acc, 0, 0, 0);
                    C[mt][j] = acc;
                }
            }
        }
        // output layer partials for this pass's 2 point-tiles
        {
            float s0 = 0.f, s1 = 0.f;
#pragma unroll
            for (int mt = 0; mt < 4; ++mt) {
                float4 wo = *(const float4*)(w_out + mt * 16 + quad * 4);
                s0 = fmaf(fmaxf(C[mt][0][0], 0.f), wo.x, s0);
                s0 = fmaf(fmaxf(C[mt][0][1], 0.f), wo.y, s0);
                s0 = fmaf(fmaxf(C[mt][0][2], 0.f), wo.z, s0);
                s0 = fmaf(fmaxf(C[mt][0][3], 0.f), wo.w, s0);
                s1 = fmaf(fmaxf(C[mt][1][0], 0.f), wo.x, s1);
                s1 = fmaf(fmaxf(C[mt][1][1], 0.f), wo.y, s1);
                s1 = fmaf(fmaxf(C[mt][1][2], 0.f), wo.z, s1);
                s1 = fmaf(fmaxf(C[mt][1][3], 0.f), wo.w, s1);
            }
            sacc[2 * h + 0] = s0;
            sacc[2 * h + 1] = s1;
        }
    }

    // ---- quad-reduce + unscale + store ----
    {
#pragma unroll
        for (int nt = 0; nt < 4; ++nt) {
            sacc[nt] += __shfl_xor(sacc[nt], 16, 64);
            sacc[nt] += __shfl_xor(sacc[nt], 32, 64);
        }
        float r = (quad & 1) ? ((quad & 2) ? sacc[3] : sacc[1])
                             : ((quad & 2) ? sacc[2] : sacc[0]);
        out[wavebase + quad * 16 + l15] = r * (1.f / 8192.f);
    }
}

// =================== FALLBACK: r7 fused kernel (used if ws too small) ========
__global__ __launch_bounds__(TPB, 4) void hashgrid_mlp_kernel(
    const float* __restrict__ x,
    const float* __restrict__ mesh_min,
    const float* __restrict__ mesh_max,
    const float* __restrict__ tables,
    const _Float16* __restrict__ ws,
    const float* __restrict__ w_out,
    float* __restrict__ out,
    int N) {
    __shared__ float2 ltab[881];
    __shared__ _Float16 encbuf[4][64][ENC_ROW];

    const int wave = threadIdx.x >> 6;
    const int lane = threadIdx.x & 63;
    const int l15 = lane & 15;
    const int quad = lane >> 4;
    const int wavebase = blockIdx.x * TPB + wave * 64;
    const int p = wavebase + lane;

    {
        const float2* t0 = (const float2*)tables;
        for (int i = threadIdx.x; i < 27; i += TPB) ltab[i] = t0[i];
        const float2* t1 = (const float2*)(tables + 1 * 524288);
        for (int i = threadIdx.x; i < 125; i += TPB) ltab[27 + i] = t1[i];
        const float2* t2 = (const float2*)(tables + 2 * 524288);
        for (int i = threadIdx.x; i < 729; i += TPB) ltab[152 + i] = t2[i];
    }

    float mn0 = mesh_min[0], mn1 = mesh_min[1], mn2 = mesh_min[2];
    float mx0 = mesh_max[0], mx1 = mesh_max[1], mx2 = mesh_max[2];
    float ux = (x[3 * p + 0] - mn0) / (mx0 - mn0);
    float uy = (x[3 * p + 1] - mn1) / (mx1 - mn1);
    float uz = (x[3 * p + 2] - mn2) / (mx2 - mn2);

    float ef[16];
    float wl[3][3];
    float2 g[24];

#pragma unroll
    for (int l = 0; l < 3; ++l) {
        const int res = 64 << l;
        const float* tab = tables + (size_t)(l + 5) * 524288;
        float px = ux * (float)res, py = uy * (float)res, pz = uz * (float)res;
        int cx = (int)floorf(px), cy = (int)floorf(py), cz = (int)floorf(pz);
        wl[l][0] = px - (float)cx;
        wl[l][1] = py - (float)cy;
        wl[l][2] = pz - (float)cz;
        uint32_t hy0 = (uint32_t)cy * 2654435761u, hy1 = (uint32_t)(cy + 1) * 2654435761u;
        uint32_t hz0 = (uint32_t)cz * 805459861u,  hz1 = (uint32_t)(cz + 1) * 805459861u;
#pragma unroll
        for (int c = 0; c < 4; ++c) {
            uint32_t hyz = ((c & 1) ? hy1 : hy0) ^ ((c & 2) ? hz1 : hz0);
            uint32_t i0 = ((uint32_t)cx ^ hyz) & 262143u;
            uint32_t i1 = ((uint32_t)(cx + 1) ^ hyz) & 262143u;
            g[l * 8 + 2 * c + 0] = *(const float2*)(tab + 2 * (size_t)i0);
            g[l * 8 + 2 * c + 1] = *(const float2*)(tab + 2 * (size_t)i1);
        }
    }

#pragma unroll
    for (int l = 3; l < 5; ++l) {
        const int res = 2 << l;
        const int s = res + 1;
        const float* tab = tables + (size_t)l * 524288;
        float px = ux * (float)res, py = uy * (float)res, pz = uz * (float)res;
        int cx = (int)floorf(px), cy = (int)floorf(py), cz = (int)floorf(pz);
        float wx = px - (float)cx, wy = py - (float)cy, wz = pz - (float)cz;
        float f0 = 0.f, f1 = 0.f;
#pragma unroll
        for (int c = 0; c < 4; ++c) {
            int Y = cy + ((c & 1) ? 1 : 0);
            int Z = cz + ((c & 2) ? 1 : 0);
            float wyz = ((c & 1) ? wy : 1.f - wy) * ((c & 2) ? wz : 1.f - wz);
            int i0 = cx + Y * s + Z * s * s;
            float4u v = *(const float4u*)(tab + 2 * (size_t)i0);
            f0 += wyz * (v.x + wx * (v.z - v.x));
            f1 += wyz * (v.y + wx * (v.w - v.y));
        }
        ef[2 * l + 0] = f0;
        ef[2 * l + 1] = f1;
    }

    __syncthreads();

#pragma unroll
    for (int l = 0; l < 3; ++l) {
        const int res = 2 << l;
        const int s = res + 1;
        const int base = (l == 0) ? 0 : (l == 1) ? 27 : 152;
        float px = ux * (float)res, py = uy * (float)res, pz = uz * (float)res;
        int cx = (int)floorf(px), cy = (int)floorf(py), cz = (int)floorf(pz);
        float wx = px - (float)cx, wy = py - (float)cy, wz = pz - (float)cz;
        float f0 = 0.f, f1 = 0.f;
#pragma unroll
        for (int c = 0; c < 4; ++c) {
            int i0 = base + cx + (cy + ((c & 1) ? 1 : 0)) * s + (cz + ((c & 2) ? 1 : 0)) * s * s;
            float wyz = ((c & 1) ? wy : 1.f - wy) * ((c & 2) ? wz : 1.f - wz);
            float2 e0 = ltab[i0];
            float2 e1 = ltab[i0 + 1];
            f0 += wyz * (e0.x + wx * (e1.x - e0.x));
            f1 += wyz * (e0.y + wx * (e1.y - e0.y));
        }
        ef[2 * l + 0] = f0;
        ef[2 * l + 1] = f1;
    }

#pragma unroll
    for (int l = 0; l < 3; ++l) {
        float wx = wl[l][0], wy = wl[l][1], wz = wl[l][2];
        float f0 = 0.f, f1 = 0.f;
#pragma unroll
        for (int c = 0; c < 4; ++c) {
            float wyz = ((c & 1) ? wy : 1.f - wy) * ((c & 2) ? wz : 1.f - wz);
            float2 e0 = g[l * 8 + 2 * c + 0];
            float2 e1 = g[l * 8 + 2 * c + 1];
            f0 += wyz * (e0.x + wx * (e1.x - e0.x));
            f1 += wyz * (e0.y + wx * (e1.y - e0.y));
        }
        ef[10 + 2 * l + 0] = f0;
        ef[10 + 2 * l + 1] = f1;
    }

#pragma unroll
    for (int v = 0; v < 4; ++v) {
        half2v lo = pkrtz(ef[4 * v + 0] * 8192.f, ef[4 * v + 1] * 8192.f);
        half2v hi = pkrtz(ef[4 * v + 2] * 8192.f, ef[4 * v + 3] * 8192.f);
        half4 t;
        t[0] = lo[0]; t[1] = lo[1]; t[2] = hi[0]; t[3] = hi[1];
        *(half4*)&encbuf[wave][lane][v * 4] = t;
    }

    floatx4 C[4][4];
    {
        half4 b[4];
#pragma unroll
        for (int nt = 0; nt < 4; ++nt)
            b[nt] = *(const half4*)&encbuf[wave][nt * 16 + l15][quad * 4];
#pragma unroll
        for (int mt = 0; mt < 4; ++mt) {
            half4 a = *(const half4*)(ws + mt * 256 + lane * 4);
#pragma unroll
            for (int nt = 0; nt < 4; ++nt) {
                floatx4 zero = {0.f, 0.f, 0.f, 0.f};
                C[mt][nt] = __builtin_amdgcn_mfma_f32_16x16x16f16(a, b[nt], zero, 0, 0, 0);
            }
        }
    }

#pragma unroll
    for (int layer = 0; layer < 3; ++layer) {
        half4 b[4][4];
#pragma unroll
        for (int kt = 0; kt < 4; ++kt)
#pragma unroll
            for (int nt = 0; nt < 4; ++nt)
                b[kt][nt] = relu_pack(C[kt][nt]);
#pragma unroll
        for (int mt = 0; mt < 4; ++mt) {
            half4 a[4];
#pragma unroll
            for (int kt = 0; kt < 4; ++kt)
                a[kt] = *(const half4*)(ws + 1024 + ((layer * 4 + kt) * 4 + mt) * 256 + lane * 4);
#pragma unroll
            for (int nt = 0; nt < 4; ++nt) {
                floatx4 acc = {0.f, 0.f, 0.f, 0.f};
#pragma unroll
                for (int kt = 0; kt < 4; ++kt)
                    acc = __builtin_amdgcn_mfma_f32_16x16x16f16(a[kt], b[kt][nt], acc, 0, 0, 0);
                C[mt][nt] = acc;
            }
        }
    }

    {
        float s[4] = {0.f, 0.f, 0.f, 0.f};
#pragma unroll
        for (int mt = 0; mt < 4; ++mt) {
            float4 wo = *(const float4*)(w_out + mt * 16 + quad * 4);
#pragma unroll
            for (int nt = 0; nt < 4; ++nt) {
                s[nt] = fmaf(fmaxf(C[mt][nt][0], 0.f), wo.x, s[nt]);
                s[nt] = fmaf(fmaxf(C[mt][nt][1], 0.f), wo.y, s[nt]);
                s[nt] = fmaf(fmaxf(C[mt][nt][2], 0.f), wo.z, s[nt]);
                s[nt] = fmaf(fmaxf(C[mt][nt][3], 0.f), wo.w, s[nt]);
            }
        }
#pragma unroll
        for (int nt = 0; nt < 4; ++nt) {
            s[nt] += __shfl_xor(s[nt], 16, 64);
            s[nt] += __shfl_xor(s[nt], 32, 64);
        }
        float r = (quad & 1) ? ((quad & 2) ? s[3] : s[1])
                             : ((quad & 2) ? s[2] : s[0]);
        out[wavebase + quad * 16 + l15] = r * (1.f / 8192.f);
    }
}

extern "C" void kernel_launch(void* const* d_in, const int* in_sizes, int n_in,
                              void* d_out, int out_size, void* d_ws,
                              size_t ws_size, hipStream_t stream) {
    const float* x        = (const float*)d_in[0];
    const float* mesh_min = (const float*)d_in[1];
    const float* mesh_max = (const float*)d_in[2];
    const float* tables   = (const float*)d_in[3];
    const float* w_in     = (const float*)d_in[4];
    const float* w_hidden = (const float*)d_in[5];
    const float* w_out    = (const float*)d_in[6];
    float* out = (float*)d_out;
    _Float16* ws = (_Float16*)d_ws;  // [0..13312): weight frags

    int N = out_size;  // 2,097,152 (multiple of 256)

    // d_ws layout: [0,32KB) weights | [32KB, +8MB) f16 tables
    size_t need = 32768 + (size_t)8 * 262144 * 4;
    if (ws_size >= need) {
        uint32_t* tf = (uint32_t*)((char*)d_ws + 32768);
        hipLaunchKernelGGL(prep_all, dim3(8244), dim3(256), 0, stream,
                           tables, tf, w_in, w_hidden, ws);
        hipLaunchKernelGGL(fused_kernel, dim3(N / TPB), dim3(TPB), 0, stream,
                           x, mesh_min, mesh_max, tables, tf, ws, w_out, out, N);
    } else {
        hipLaunchKernelGGL(prep_weights, dim3(52), dim3(256), 0, stream,
                           w_in, w_hidden, ws);
        hipLaunchKernelGGL(hashgrid_mlp_kernel, dim3(N / TPB), dim3(TPB), 0, stream,
                           x, mesh_min, mesh_max, tables, ws, w_out, out, N);
    }
}